// Round 1
// baseline (9986.720 us; speedup 1.0000x reference)
//
#include <hip/hip_runtime.h>

// LSTM on MI355X. Strategy: per-timestep kernels (512 launches) doing
// [64,1536]@[1536,4096] with split-bf16 (hi/lo) MFMA = pseudo-fp32 accuracy.
// Weights pre-packed once per call into MFMA B-fragment layout (hi/lo planes).
// Block = 4 latent cols x 4 gates = 16 gate-cols; 4 waves = 4 x 16 batch rows.

namespace {
constexpr int T_STEPS = 512;
constexpr int BATCH   = 64;
constexpr int DI      = 512;
constexpr int DL      = 1024;
constexpr int NKC     = 48;   // K=1536 in chunks of 32
constexpr int NKC_H   = 32;   // h-part chunks (K=1024)
}

typedef __attribute__((ext_vector_type(8))) short bf16x8;
typedef __attribute__((ext_vector_type(8))) unsigned short u16x8;
typedef __attribute__((ext_vector_type(4))) float f32x4;

__device__ __forceinline__ unsigned short f2bf(float x){
  unsigned int u = __float_as_uint(x);
  return (unsigned short)((u + 0x7FFFu + ((u >> 16) & 1u)) >> 16);
}
__device__ __forceinline__ float bf2f(unsigned short b){
  return __uint_as_float(((unsigned int)b) << 16);
}

// ---------------- prep: embeddings -> bf16 [T*B][DI] ----------------
__global__ void prep_xe(const int* __restrict__ X, const float* __restrict__ emb,
                        unsigned short* __restrict__ xe){
  int i = blockIdx.x * blockDim.x + threadIdx.x;      // one thread per 8 elems
  const int total = T_STEPS * BATCH * DI / 8;         // 2,097,152
  if (i >= total) return;
  int row = i >> 6;            // DI/8 = 64 segments per row; row = t*64+b
  int seg = i & 63;
  int tok = X[row];
  const float* src = emb + (long long)tok * DI + seg * 8;
  float4 v0 = *(const float4*)src;
  float4 v1 = *(const float4*)(src + 4);
  u16x8 o;
  o[0]=f2bf(v0.x); o[1]=f2bf(v0.y); o[2]=f2bf(v0.z); o[3]=f2bf(v0.w);
  o[4]=f2bf(v1.x); o[5]=f2bf(v1.y); o[6]=f2bf(v1.z); o[7]=f2bf(v1.w);
  *(u16x8*)(xe + (long long)row * DI + seg * 8) = o;
}

// ---------------- prep: pack W into MFMA B-fragment layout, hi/lo ----------------
// Fragment for (bk, kc): lane l holds W[k = kc*32 + (l>>4)*8 + j][gatecol(bk, l&15)]
// where local col lc = l&15 -> gate g = lc>>2 (f,i,c,o), latent j = bk*4 + (lc&3).
__global__ void prep_w(const float* __restrict__ Wf, const float* __restrict__ Wi,
                       const float* __restrict__ Wc, const float* __restrict__ Wo,
                       unsigned short* __restrict__ W_hi, unsigned short* __restrict__ W_lo){
  int idx = blockIdx.x * blockDim.x + threadIdx.x;    // 256*48*64 threads
  if (idx >= 256 * NKC * 64) return;
  int lane = idx & 63;
  int kc   = (idx >> 6) % NKC;
  int bk   = idx / (64 * NKC);
  int lc = lane & 15, kg = lane >> 4;
  int g  = lc >> 2;
  int jl = bk * 4 + (lc & 3);
  const float* Wg = (g == 0) ? Wf : ((g == 1) ? Wi : ((g == 2) ? Wc : Wo));
  int kbase = kc * 32 + kg * 8;
  u16x8 hi, lo;
#pragma unroll
  for (int j = 0; j < 8; j++){
    float wv = Wg[(long long)(kbase + j) * DL + jl];
    unsigned short h = f2bf(wv);
    hi[j] = h;
    lo[j] = f2bf(wv - bf2f(h));
  }
  *(u16x8*)(W_hi + ((long long)(bk * NKC + kc) * 64 + lane) * 8) = hi;
  if (kc < NKC_H)
    *(u16x8*)(W_lo + ((long long)(bk * NKC_H + kc) * 64 + lane) * 8) = lo;
}

// ---------------- prep: h0 -> hi/lo planes, c=0, bias pack ----------------
__global__ void prep_h(const float* __restrict__ h0,
                       const float* __restrict__ bf_, const float* __restrict__ bi_,
                       const float* __restrict__ bc_, const float* __restrict__ bo_,
                       unsigned short* __restrict__ h_hi, unsigned short* __restrict__ h_lo,
                       float* __restrict__ c_state, float* __restrict__ bias_pack){
  int i = blockIdx.x * blockDim.x + threadIdx.x;
  if (i < BATCH * DL){
    float v = h0[i];
    unsigned short hb = f2bf(v);
    h_hi[i] = hb;
    h_lo[i] = f2bf(v - bf2f(hb));
    c_state[i] = 0.0f;
  }
  if (i < 4096){
    int r = i & 3, g = (i >> 2) & 3, bk = i >> 4;
    const float* bg = (g == 0) ? bf_ : ((g == 1) ? bi_ : ((g == 2) ? bc_ : bo_));
    bias_pack[i] = bg[bk * 4 + r];
  }
}

// ---------------- one LSTM timestep ----------------
// grid 256 blocks (4 latent cols each) x 256 threads (4 waves x 16 batch rows).
__launch_bounds__(256)
__global__ void lstm_step(const unsigned short* __restrict__ xe_t,
                          const unsigned short* __restrict__ W_hi,
                          const unsigned short* __restrict__ W_lo,
                          const unsigned short* __restrict__ h_hi_r,
                          const unsigned short* __restrict__ h_lo_r,
                          unsigned short* __restrict__ h_hi_w,
                          unsigned short* __restrict__ h_lo_w,
                          float* __restrict__ c_state,
                          const float* __restrict__ bias_pack,
                          float* __restrict__ out_t){
  __shared__ unsigned short lds_hi[NKC * 512];   // 48 KB: hi frags, all 48 kc
  __shared__ unsigned short lds_lo[16 * 512];    // 16 KB: lo frags, 16 kc at a time
  const int tid  = threadIdx.x;
  const int bk   = blockIdx.x;
  const int w    = tid >> 6;
  const int lane = tid & 63;

  // stage W hi (48KB) + lo chunk0 (kc 0..15, 16KB) into LDS
  const uint4* srcHi = (const uint4*)(W_hi + (long long)bk * NKC * 512);
  uint4* dHi = (uint4*)lds_hi;
  for (int i = tid; i < 3072; i += 256) dHi[i] = srcHi[i];
  const uint4* srcLo = (const uint4*)(W_lo + (long long)bk * NKC_H * 512);
  uint4* dLo = (uint4*)lds_lo;
  for (int i = tid; i < 1024; i += 256) dLo[i] = srcLo[i];
  __syncthreads();

  f32x4 acc = {0.f, 0.f, 0.f, 0.f};
  const int rowb = (w << 4) + (lane & 15);       // A-frag batch row
  const int kg   = lane >> 4;
  const unsigned short* hRowHi = h_hi_r + rowb * DL + kg * 8;
  const unsigned short* hRowLo = h_lo_r + rowb * DL + kg * 8;
  const unsigned short* xRow   = xe_t   + rowb * DI + kg * 8;

  // h-part, kc 0..15: 3-term split-bf16
#pragma unroll 4
  for (int kc = 0; kc < 16; kc++){
    bf16x8 ah = *(const bf16x8*)(hRowHi + kc * 32);
    bf16x8 al = *(const bf16x8*)(hRowLo + kc * 32);
    bf16x8 bh = *(const bf16x8*)(lds_hi + kc * 512 + lane * 8);
    bf16x8 bl = *(const bf16x8*)(lds_lo + kc * 512 + lane * 8);
    acc = __builtin_amdgcn_mfma_f32_16x16x32_bf16(ah, bh, acc, 0, 0, 0);
    acc = __builtin_amdgcn_mfma_f32_16x16x32_bf16(ah, bl, acc, 0, 0, 0);
    acc = __builtin_amdgcn_mfma_f32_16x16x32_bf16(al, bh, acc, 0, 0, 0);
  }
  // x-part, kc 32..47: single-term bf16 (tiny magnitudes, error negligible)
#pragma unroll 4
  for (int kc = 0; kc < 16; kc++){
    bf16x8 ax = *(const bf16x8*)(xRow + kc * 32);
    bf16x8 bh = *(const bf16x8*)(lds_hi + (NKC_H + kc) * 512 + lane * 8);
    acc = __builtin_amdgcn_mfma_f32_16x16x32_bf16(ax, bh, acc, 0, 0, 0);
  }
  __syncthreads();
  // restage lo chunk1 (kc 16..31)
  for (int i = tid; i < 1024; i += 256) dLo[i] = srcLo[1024 + i];
  __syncthreads();
#pragma unroll 4
  for (int kc = 16; kc < 32; kc++){
    bf16x8 ah = *(const bf16x8*)(hRowHi + kc * 32);
    bf16x8 al = *(const bf16x8*)(hRowLo + kc * 32);
    bf16x8 bh = *(const bf16x8*)(lds_hi + kc * 512 + lane * 8);
    bf16x8 bl = *(const bf16x8*)(lds_lo + (kc - 16) * 512 + lane * 8);
    acc = __builtin_amdgcn_mfma_f32_16x16x32_bf16(ah, bh, acc, 0, 0, 0);
    acc = __builtin_amdgcn_mfma_f32_16x16x32_bf16(ah, bl, acc, 0, 0, 0);
    acc = __builtin_amdgcn_mfma_f32_16x16x32_bf16(al, bh, acc, 0, 0, 0);
  }

  // epilogue: D[row=(lane>>4)*4+r][col=lane&15]; col lc = g*4 + (j within block)
  const int lc = lane & 15;
  const int g  = lc >> 2;
  const float bias = bias_pack[bk * 16 + lc];
  const int srcBase = (lane & 48) | (lc & 3);
#pragma unroll
  for (int r = 0; r < 4; r++){
    float v = acc[r] + bias;
    float vF = __shfl(v, srcBase);
    float vI = __shfl(v, srcBase + 4);
    float vC = __shfl(v, srcBase + 8);
    float vO = __shfl(v, srcBase + 12);
    if (g == 0){
      int b = (w << 4) | (kg << 2) | r;
      int j = (bk << 2) | (lc & 3);
      float ft = 1.f / (1.f + __expf(-vF));
      float it = 1.f / (1.f + __expf(-vI));
      float gt = tanhf(vC);
      float ot = 1.f / (1.f + __expf(-vO));
      int ci = b * DL + j;
      float cn = ft * c_state[ci] + it * gt;
      c_state[ci] = cn;
      float hn = ot * tanhf(cn);
      out_t[ci] = hn;
      unsigned short hb = f2bf(hn);
      h_hi_w[ci] = hb;
      h_lo_w[ci] = f2bf(hn - bf2f(hb));
    }
  }
}

extern "C" void kernel_launch(void* const* d_in, const int* in_sizes, int n_in,
                              void* d_out, int out_size, void* d_ws, size_t ws_size,
                              hipStream_t stream){
  const int*   X   = (const int*)d_in[0];
  const float* h0  = (const float*)d_in[1];
  const float* emb = (const float*)d_in[2];
  const float* Wf  = (const float*)d_in[3];
  const float* bf_ = (const float*)d_in[4];
  const float* Wi  = (const float*)d_in[5];
  const float* bi_ = (const float*)d_in[6];
  const float* Wc  = (const float*)d_in[7];
  const float* bc_ = (const float*)d_in[8];
  const float* Wo  = (const float*)d_in[9];
  const float* bo_ = (const float*)d_in[10];
  float* out = (float*)d_out;

  // workspace layout (~55.3 MB total)
  char* ws = (char*)d_ws;
  size_t off = 0;
  auto alloc = [&](size_t bytes) -> void* {
    void* p = ws + off;
    off = (off + bytes + 255) & ~((size_t)255);
    return p;
  };
  unsigned short* xe        = (unsigned short*)alloc(sizeof(unsigned short) * (size_t)T_STEPS * BATCH * DI);
  unsigned short* W_hi      = (unsigned short*)alloc(sizeof(unsigned short) * (size_t)256 * NKC * 512);
  unsigned short* W_lo      = (unsigned short*)alloc(sizeof(unsigned short) * (size_t)256 * NKC_H * 512);
  unsigned short* h_hi      = (unsigned short*)alloc(sizeof(unsigned short) * 2 * BATCH * DL);
  unsigned short* h_lo      = (unsigned short*)alloc(sizeof(unsigned short) * 2 * BATCH * DL);
  float*          c_state   = (float*)alloc(sizeof(float) * BATCH * DL);
  float*          bias_pack = (float*)alloc(sizeof(float) * 4096);
  (void)ws_size; (void)in_sizes; (void)n_in; (void)out_size;

  hipLaunchKernelGGL(prep_xe, dim3(8192), dim3(256), 0, stream, X, emb, xe);
  hipLaunchKernelGGL(prep_w,  dim3(3072), dim3(256), 0, stream, Wf, Wi, Wc, Wo, W_hi, W_lo);
  hipLaunchKernelGGL(prep_h,  dim3(256),  dim3(256), 0, stream, h0, bf_, bi_, bc_, bo_,
                     h_hi, h_lo, c_state, bias_pack);

  for (int t = 0; t < T_STEPS; t++){
    int rb = t & 1;
    hipLaunchKernelGGL(lstm_step, dim3(256), dim3(256), 0, stream,
                       xe + (size_t)t * BATCH * DI, W_hi, W_lo,
                       h_hi + (size_t)rb * BATCH * DL,
                       h_lo + (size_t)rb * BATCH * DL,
                       h_hi + (size_t)(rb ^ 1) * BATCH * DL,
                       h_lo + (size_t)(rb ^ 1) * BATCH * DL,
                       c_state, bias_pack,
                       out + (size_t)t * BATCH * DL);
  }
}